// Round 2
// baseline (1261.789 us; speedup 1.0000x reference)
//
#include <hip/hip_runtime.h>
#include <math.h>

#define N_CB 4
#define M_CB 1024
#define D_CB 64
#define L_CB 16
#define B_CB 4096
#define BLQ  65536   // B*L per codebook

static constexpr float DECAY_F  = 0.999f;
static constexpr float OMD_F    = 0.001f;    // fl32(1-0.999) == fl32(0.001)
static constexpr float EPS_F    = 1e-5f;
static constexpr float MEPS_F   = 0.01024f;  // M*EPS
static constexpr float COMMIT_F = 0.05f;
static constexpr float MARGIN_F = 3e-5f;     // pass-A accept margin (bound ~1.9e-5)

// d_out offsets (in floats), reference return order
static constexpr size_t ZQ_OFF   = 0;          // 16777216
static constexpr size_t LOSS_OFF = 16777216;   // 1
static constexpr size_t PERP_OFF = 16777217;   // 1
static constexpr size_t IDX_OFF  = 16777218;   // 262144 (b, n, l)
static constexpr size_t ZQ2_OFF  = 17039362;   // 16777216 (== z_q values)
static constexpr size_t EMB_OFF  = 33816578;   // 262144
static constexpr size_t CNT_OFF  = 34078722;   // 4096
static constexpr size_t EMW_OFF  = 34082818;   // 262144

// ws offsets (bytes)
static constexpr size_t WS_COUNTS  = 0;         // u32 N*M   = 16384
static constexpr size_t WS_DW      = 16384;     // f32 N*M*D = 1048576
static constexpr size_t WS_NFLAG   = 1064960;   // u32
static constexpr size_t WS_LOSS    = 1064968;   // f64
static constexpr size_t WS_ENT     = 1064976;   // f64 * 4
static constexpr size_t WS_SE      = 1065008;   // f32 N*M   = 16384
static constexpr size_t WS_IDX     = 1081392;   // i32 N*BLQ = 1048576
static constexpr size_t WS_FLAGGED = 2129968;   // u32 N*BLQ = 1048576 (worst case)

// ---- numpy pairwise_sum (n=64) emulation of sum(v*v): 8 accumulators ----
__device__ __forceinline__ float np_sumsq64(const float* __restrict__ v) {
  float r[8];
#pragma unroll
  for (int t = 0; t < 8; ++t) r[t] = __fmul_rn(v[t], v[t]);
#pragma unroll
  for (int i = 8; i < 64; i += 8) {
#pragma unroll
    for (int t = 0; t < 8; ++t)
      r[t] = __fadd_rn(r[t], __fmul_rn(v[i + t], v[i + t]));
  }
  return __fadd_rn(__fadd_rn(__fadd_rn(r[0], r[1]), __fadd_rn(r[2], r[3])),
                   __fadd_rn(__fadd_rn(r[4], r[5]), __fadd_rn(r[6], r[7])));
}

// -------- kernel 1: Se[n][m] = np.sum(e**2, -1), numpy order --------
__global__ __launch_bounds__(256) void se_kernel(const float* __restrict__ emb,
                                                 float* __restrict__ se) {
  const int j = blockIdx.x * 256 + threadIdx.x;  // < N*M = 4096
  se[j] = np_sumsq64(emb + (size_t)j * 64);
}

// -------- kernel 2 (pass A): fast argmin + flag near-ties --------
__global__ __launch_bounds__(256) void argmin_kernel(
    const float* __restrict__ x, const float* __restrict__ emb,
    const float* __restrict__ se, int* __restrict__ out_idx,
    unsigned* __restrict__ counts, float* __restrict__ out,
    unsigned* __restrict__ nflag, unsigned* __restrict__ flagged) {
  const int n = blockIdx.y;
  const int k = blockIdx.x * 256 + threadIdx.x;   // query within codebook
  const int b = k >> 4, l = k & 15;
  const float* xp = x + (size_t)b * 4096 + (size_t)n * 1024 + l;
  float xr[64];
#pragma unroll
  for (int d = 0; d < 64; ++d) xr[d] = xp[d * 16];

  const float* en  = emb + (size_t)n * (M_CB * D_CB);
  const float* sen = se + (size_t)n * M_CB;

  float best1 = 3.4e38f, best2 = 3.4e38f;
  int bidx = 0;
#pragma unroll 2
  for (int m = 0; m < M_CB; ++m) {
    const float* er = en + m * 64;
    float dot = 0.f;
#pragma unroll
    for (int d = 0; d < 64; ++d) dot = fmaf(er[d], xr[d], dot);
    const float t = fmaf(-2.f, dot, sen[m]);
    const bool lt1 = t < best1;
    const bool lt2 = t < best2;
    best2 = lt1 ? best1 : (lt2 ? t : best2);
    best1 = lt1 ? t : best1;
    bidx  = lt1 ? m : bidx;
  }
  if (best2 - best1 < MARGIN_F) {       // near-tie vs np fp32 ref: exact pass
    const unsigned slot = atomicAdd(nflag, 1u);
    flagged[slot] = (unsigned)(n * BLQ + k);
  }
  out_idx[(size_t)n * BLQ + k] = bidx;
  out[IDX_OFF + (size_t)b * 64 + (size_t)n * 16 + l] = (float)bidx;
  atomicAdd(&counts[n * M_CB + bidx], 1u);
}

// -------- kernel 2b (pass B): bit-exact numpy fp32 emulation for flagged ----
// distance = fl( fl(Sx + Se[m]) - fl(2*dot) ), dot in numpy-einsum SSE order:
// lane j accum over i ≡ j (mod 4) sequential; final fl(fl(l3+l2)+fl(l1+l0)).
__global__ __launch_bounds__(64) void exact_kernel(
    const float* __restrict__ x, const float* __restrict__ emb,
    const float* __restrict__ se, const unsigned* __restrict__ nflag,
    const unsigned* __restrict__ flagged, int* __restrict__ out_idx,
    unsigned* __restrict__ counts, float* __restrict__ out) {
  __shared__ float xs[64];
  const unsigned cnt = *nflag;
  const int lane = threadIdx.x;
  for (unsigned q = blockIdx.x; q < cnt; q += gridDim.x) {
    const unsigned code = flagged[q];
    const int n = code >> 16;          // BLQ == 65536
    const int k = (int)(code & 65535u);
    const int b = k >> 4, l = k & 15;
    __syncthreads();
    xs[lane] = x[(size_t)b * 4096 + (size_t)n * 1024 + lane * 16 + l];
    __syncthreads();
    const float sx = np_sumsq64(xs);   // numpy pairwise order (broadcast reads)
    const float* en  = emb + (size_t)n * (M_CB * D_CB);
    const float* sen = se + (size_t)n * M_CB;
    float bt = 3.4e38f;
    int bm = 0;
    for (int mm = 0; mm < 16; ++mm) {
      const int m = lane * 16 + mm;    // ascending per lane, contiguous blocks
      const float* er = en + m * 64;
      float l0 = 0.f, l1 = 0.f, l2 = 0.f, l3 = 0.f;
#pragma unroll
      for (int d = 0; d < 64; d += 4) {
        l0 = __fadd_rn(l0, __fmul_rn(xs[d],     er[d]));
        l1 = __fadd_rn(l1, __fmul_rn(xs[d + 1], er[d + 1]));
        l2 = __fadd_rn(l2, __fmul_rn(xs[d + 2], er[d + 2]));
        l3 = __fadd_rn(l3, __fmul_rn(xs[d + 3], er[d + 3]));
      }
      const float dot = __fadd_rn(__fadd_rn(l3, l2), __fadd_rn(l1, l0));
      const float t = __fsub_rn(__fadd_rn(sx, sen[m]), __fmul_rn(2.0f, dot));
      if (t < bt) { bt = t; bm = m; }  // strict <: first-occurrence within lane
    }
    // cross-lane reduce, first-occurrence tie-break (smaller m wins on ties)
    for (int off = 32; off; off >>= 1) {
      const float ot = __shfl_xor(bt, off, 64);
      const int   om = __shfl_xor(bm, off, 64);
      if (ot < bt || (ot == bt && om < bm)) { bt = ot; bm = om; }
    }
    if (lane == 0) {
      const int old = out_idx[(size_t)n * BLQ + k];
      if (old != bm) {
        out_idx[(size_t)n * BLQ + k] = bm;
        out[IDX_OFF + (size_t)b * 64 + (size_t)n * 16 + l] = (float)bm;
        atomicSub(&counts[n * M_CB + old], 1u);
        atomicAdd(&counts[n * M_CB + bm], 1u);
      }
    }
  }
}

// -------- kernel 3: fused epilogue: z_q, encodings_zq, loss partial, dw ----
__global__ __launch_bounds__(256) void epilogue_kernel(
    const float* __restrict__ x, const float* __restrict__ emb,
    const int* __restrict__ idxs, float* __restrict__ out,
    float* __restrict__ dw, double* __restrict__ loss_acc) {
  const int j = blockIdx.x * 256 + threadIdx.x;
  const size_t i = (size_t)j * 4;                       // 4 consecutive l's
  const int l0 = (int)(i & 15), d = (int)((i >> 4) & 63);
  const int n = (int)((i >> 10) & 3), b = (int)(i >> 12);
  const int kbase = b * 16 + l0;
  const int4 idx4 = *(const int4*)(idxs + (size_t)n * BLQ + kbase);
  const float4 xv = *(const float4*)(x + i);
  const float e0 = emb[((size_t)(n * M_CB + idx4.x) << 6) + d];
  const float e1 = emb[((size_t)(n * M_CB + idx4.y) << 6) + d];
  const float e2 = emb[((size_t)(n * M_CB + idx4.z) << 6) + d];
  const float e3 = emb[((size_t)(n * M_CB + idx4.w) << 6) + d];
  *(float4*)(out + i) = make_float4(e0, e1, e2, e3);
  float2* zq2 = (float2*)(out + ZQ2_OFF + i);           // ZQ2_OFF%4==2: 8B-aligned
  zq2[0] = make_float2(e0, e1);
  zq2[1] = make_float2(e2, e3);
  atomicAdd(&dw[((size_t)(n * M_CB + idx4.x) << 6) + d], xv.x);
  atomicAdd(&dw[((size_t)(n * M_CB + idx4.y) << 6) + d], xv.y);
  atomicAdd(&dw[((size_t)(n * M_CB + idx4.z) << 6) + d], xv.z);
  atomicAdd(&dw[((size_t)(n * M_CB + idx4.w) << 6) + d], xv.w);
  const float d0 = xv.x - e0, d1 = xv.y - e1, d2 = xv.z - e2, d3 = xv.w - e3;
  float v = d0 * d0 + d1 * d1 + d2 * d2 + d3 * d3;
#pragma unroll
  for (int off = 32; off; off >>= 1) v += __shfl_down(v, off, 64);
  __shared__ float part[4];
  if ((threadIdx.x & 63) == 0) part[threadIdx.x >> 6] = v;
  __syncthreads();
  if (threadIdx.x == 0)
    atomicAdd(loss_acc, (double)(part[0] + part[1] + part[2] + part[3]));
}

// -------- kernel 4: smoothed EMA counts + per-codebook entropy --------
__global__ __launch_bounds__(1024) void ema_count_kernel(
    const unsigned* __restrict__ counts, const float* __restrict__ ema_count_in,
    float* __restrict__ out, double* __restrict__ entropy) {
  __shared__ float sdata[1024];
  const int n = blockIdx.x, m = threadIdx.x;
  const unsigned c = counts[n * M_CB + m];
  const float c1 = DECAY_F * ema_count_in[n * M_CB + m] + OMD_F * (float)c;
  sdata[m] = c1;
  __syncthreads();
  for (int s = 512; s > 0; s >>= 1) {
    if (m < s) sdata[m] += sdata[m + s];
    __syncthreads();
  }
  const float nsum = sdata[0];
  __syncthreads();
  out[CNT_OFF + (size_t)n * M_CB + m] = (c1 + EPS_F) / (nsum + MEPS_F) * nsum;
  const float p = (float)c * (1.0f / 65536.0f);
  sdata[m] = p * logf(p + 1e-10f);   // p==0 -> 0 exactly
  __syncthreads();
  for (int s = 512; s > 0; s >>= 1) {
    if (m < s) sdata[m] += sdata[m + s];
    __syncthreads();
  }
  if (m == 0) entropy[n] = -(double)sdata[0];
}

// -------- kernel 5: new_ema_weight + new_embedding --------
__global__ __launch_bounds__(256) void ema_weight_kernel(
    const float* __restrict__ ema_w, const float* __restrict__ dw,
    float* __restrict__ out) {
  const int j = blockIdx.x * 256 + threadIdx.x;  // < N*M*D = 262144
  const float w = DECAY_F * ema_w[j] + OMD_F * dw[j];
  out[EMW_OFF + j] = w;
  out[EMB_OFF + j] = w / out[CNT_OFF + (j >> 6)];
}

// -------- kernel 6: scalars --------
__global__ void scalars_kernel(const double* __restrict__ loss_acc,
                               const double* __restrict__ entropy,
                               float* __restrict__ out) {
  if (threadIdx.x == 0 && blockIdx.x == 0) {
    out[LOSS_OFF] = (float)((double)COMMIT_F * loss_acc[0] * (1.0 / 16777216.0));
    out[PERP_OFF] = (float)(exp(entropy[0]) + exp(entropy[1]) +
                            exp(entropy[2]) + exp(entropy[3]));
  }
}

extern "C" void kernel_launch(void* const* d_in, const int* in_sizes, int n_in,
                              void* d_out, int out_size, void* d_ws, size_t ws_size,
                              hipStream_t stream) {
  const float* x        = (const float*)d_in[0];
  const float* emb      = (const float*)d_in[1];
  const float* ema_cnt  = (const float*)d_in[2];
  const float* ema_wgt  = (const float*)d_in[3];
  float* out = (float*)d_out;
  char* ws = (char*)d_ws;
  unsigned* counts  = (unsigned*)(ws + WS_COUNTS);
  float*    dw      = (float*)(ws + WS_DW);
  unsigned* nflag   = (unsigned*)(ws + WS_NFLAG);
  double*   lacc    = (double*)(ws + WS_LOSS);
  double*   ent     = (double*)(ws + WS_ENT);
  float*    se      = (float*)(ws + WS_SE);
  int*      idxs    = (int*)(ws + WS_IDX);
  unsigned* flagged = (unsigned*)(ws + WS_FLAGGED);

  // zero counts+dw+nflag+loss in one shot (ws is poisoned each call)
  hipMemsetAsync(ws, 0, WS_ENT, stream);

  se_kernel<<<16, 256, 0, stream>>>(emb, se);
  argmin_kernel<<<dim3(BLQ / 256, N_CB), 256, 0, stream>>>(
      x, emb, se, idxs, counts, out, nflag, flagged);
  exact_kernel<<<256, 64, 0, stream>>>(x, emb, se, nflag, flagged, idxs,
                                       counts, out);
  epilogue_kernel<<<16384, 256, 0, stream>>>(x, emb, idxs, out, dw, lacc);
  ema_count_kernel<<<N_CB, 1024, 0, stream>>>(counts, ema_cnt, out, ent);
  ema_weight_kernel<<<1024, 256, 0, stream>>>(ema_wgt, dw, out);
  scalars_kernel<<<1, 64, 0, stream>>>(lacc, ent, out);
}

// Round 3
// 678.149 us; speedup vs baseline: 1.8606x; 1.8606x over previous
//
#include <hip/hip_runtime.h>
#include <math.h>

#define N_CB 4
#define M_CB 1024
#define D_CB 64
#define L_CB 16
#define B_CB 4096
#define BLQ  65536   // B*L per codebook

static constexpr float DECAY_F  = 0.999f;
static constexpr float OMD_F    = 0.001f;
static constexpr float EPS_F    = 1e-5f;
static constexpr float MEPS_F   = 0.01024f;  // M*EPS
static constexpr float COMMIT_F = 0.05f;
static constexpr float MARGIN_F = 6e-5f;     // > 2*(np-ref err ~1.5e-5 + mfma err ~7e-6)

// d_out offsets (in floats), reference return order
static constexpr size_t ZQ_OFF   = 0;          // 16777216
static constexpr size_t LOSS_OFF = 16777216;   // 1
static constexpr size_t PERP_OFF = 16777217;   // 1
static constexpr size_t IDX_OFF  = 16777218;   // 262144 (b, n, l)
static constexpr size_t ZQ2_OFF  = 17039362;   // 16777216 (== z_q values)
static constexpr size_t EMB_OFF  = 33816578;   // 262144
static constexpr size_t CNT_OFF  = 34078722;   // 4096
static constexpr size_t EMW_OFF  = 34082818;   // 262144

// ws offsets (bytes)
static constexpr size_t WS_COUNTS  = 0;         // u32 N*M   = 16384
static constexpr size_t WS_DW      = 16384;     // f32 N*M*D = 1048576
static constexpr size_t WS_NFLAG   = 1064960;   // u32
static constexpr size_t WS_LOSS    = 1064968;   // f64
static constexpr size_t WS_ENT     = 1064976;   // f64 * 4
static constexpr size_t WS_SE      = 1065008;   // f32 N*M   = 16384
static constexpr size_t WS_IDX     = 1081392;   // i32 N*BLQ = 1048576
static constexpr size_t WS_FLAGGED = 2129968;   // u32 N*BLQ = 1048576 (worst case)
static constexpr size_t WS_EH      = 3178544;   // u16 N*M*D = 524288 (16B aligned)
static constexpr size_t WS_EL      = 3702832;   // u16 N*M*D = 524288 (16B aligned)

typedef __attribute__((ext_vector_type(8))) short short8;
typedef __attribute__((ext_vector_type(8))) unsigned short ushort8;
typedef __attribute__((ext_vector_type(4))) float f32x4;

__device__ __forceinline__ unsigned short bf16_rne(float f) {
  unsigned u = __float_as_uint(f);
  return (unsigned short)((u + 0x7FFFu + ((u >> 16) & 1u)) >> 16);
}
__device__ __forceinline__ float bf16_tof(unsigned short h) {
  return __uint_as_float((unsigned)h << 16);
}

// ---- numpy pairwise_sum (n=64) emulation of sum(v*v): 8 accumulators ----
__device__ __forceinline__ float np_sumsq64(const float* __restrict__ v) {
  float r[8];
#pragma unroll
  for (int t = 0; t < 8; ++t) r[t] = __fmul_rn(v[t], v[t]);
#pragma unroll
  for (int i = 8; i < 64; i += 8) {
#pragma unroll
    for (int t = 0; t < 8; ++t)
      r[t] = __fadd_rn(r[t], __fmul_rn(v[i + t], v[i + t]));
  }
  return __fadd_rn(__fadd_rn(__fadd_rn(r[0], r[1]), __fadd_rn(r[2], r[3])),
                   __fadd_rn(__fadd_rn(r[4], r[5]), __fadd_rn(r[6], r[7])));
}

// -------- kernel 1: Se[n][m] = np.sum(e**2, -1), numpy order --------
__global__ __launch_bounds__(256) void se_kernel(const float* __restrict__ emb,
                                                 float* __restrict__ se) {
  const int j = blockIdx.x * 256 + threadIdx.x;  // < N*M = 4096
  se[j] = np_sumsq64(emb + (size_t)j * 64);
}

// -------- kernel 1b: codebook -> bf16 hi/lo split --------
__global__ __launch_bounds__(256) void ebf_kernel(const float* __restrict__ emb,
                                                  unsigned short* __restrict__ ehg,
                                                  unsigned short* __restrict__ elg) {
  const int j = blockIdx.x * 256 + threadIdx.x;  // < 262144
  const float v = emb[j];
  const unsigned short h = bf16_rne(v);
  ehg[j] = h;
  elg[j] = bf16_rne(v - bf16_tof(h));
}

// -------- kernel 2 (pass A): fused MFMA GEMM + argmin + near-tie flagging ----
// t_m = Se[m] - 2*x.e_m ; dot via bf16-split: xh*eh + xh*el + xl*eh
__global__ __launch_bounds__(256, 2) void mfma_argmin_kernel(
    const float* __restrict__ x, const unsigned short* __restrict__ ehg,
    const unsigned short* __restrict__ elg, const float* __restrict__ se,
    int* __restrict__ out_idx, unsigned* __restrict__ counts,
    float* __restrict__ out, unsigned* __restrict__ nflag,
    unsigned* __restrict__ flagged) {
  __shared__ unsigned short xh[128][72], xl[128][72];   // pad 64->72: 2-way banks
  __shared__ unsigned short eh[128][72], el[128][72];
  __shared__ float se_s[M_CB];
  const int tid = threadIdx.x;
  const int n = blockIdx.y;
  const int q0 = blockIdx.x * 128;

  // ---- stage x tile (coalesced float4) -> bf16 hi/lo, layout [q][d] ----
  {
    const int bloc = tid >> 5;          // 0..7 : which b
    const int ti = tid & 31;
    const float* xb = x + ((size_t)((q0 >> 4) + bloc)) * 4096 + n * 1024;
#pragma unroll
    for (int r = 0; r < 8; ++r) {
      const int t = ti * 4 + r * 128;   // 4 consecutive l, same d
      const float4 v = *(const float4*)(xb + t);
      const int d = t >> 4, l = t & 15;
      const int qr = bloc * 16 + l;
      const float vv[4] = {v.x, v.y, v.z, v.w};
#pragma unroll
      for (int j = 0; j < 4; ++j) {
        const unsigned short h = bf16_rne(vv[j]);
        xh[qr + j][d] = h;
        xl[qr + j][d] = bf16_rne(vv[j] - bf16_tof(h));
      }
    }
    *(float4*)&se_s[tid * 4] = *(const float4*)(se + n * M_CB + tid * 4);
  }
  __syncthreads();

  const int wv = tid >> 6, ln = tid & 63;
  const int col = ln & 15, quad = ln >> 4;

  // ---- A fragments (held for whole kernel): rows wv*32 + t*16 + col ----
  short8 ah[2][2], al[2][2];
#pragma unroll
  for (int t = 0; t < 2; ++t)
#pragma unroll
    for (int kh = 0; kh < 2; ++kh) {
      const int qq = wv * 32 + t * 16 + col;
      const int kk = kh * 32 + quad * 8;
      ah[t][kh] = *(const short8*)&xh[qq][kk];
      al[t][kh] = *(const short8*)&xl[qq][kk];
    }

  float b1[2][4], b2[2][4];
  int bi[2][4];
#pragma unroll
  for (int t = 0; t < 2; ++t)
#pragma unroll
    for (int r = 0; r < 4; ++r) { b1[t][r] = 3.4e38f; b2[t][r] = 3.4e38f; bi[t][r] = 0; }

  const unsigned short* ehn = ehg + (size_t)n * (M_CB * D_CB);
  const unsigned short* eln = elg + (size_t)n * (M_CB * D_CB);
  const int prow = tid >> 3, pseg = (tid & 7) << 3;   // staging coords

  // prefetch chunk 0 into registers
  ushort8 ph[4], pl[4];
#pragma unroll
  for (int rr = 0; rr < 4; ++rr) {
    const size_t off = ((size_t)(rr * 32 + prow) << 6) + pseg;
    ph[rr] = *(const ushort8*)(ehn + off);
    pl[rr] = *(const ushort8*)(eln + off);
  }

  for (int c = 0; c < 8; ++c) {
    __syncthreads();                    // prev chunk's ds_reads done
#pragma unroll
    for (int rr = 0; rr < 4; ++rr) {
      *(ushort8*)&eh[rr * 32 + prow][pseg] = ph[rr];
      *(ushort8*)&el[rr * 32 + prow][pseg] = pl[rr];
    }
    if (c < 7) {                        // prefetch next chunk (hidden by MFMA)
#pragma unroll
      for (int rr = 0; rr < 4; ++rr) {
        const size_t off = ((size_t)((c + 1) * 128 + rr * 32 + prow) << 6) + pseg;
        ph[rr] = *(const ushort8*)(ehn + off);
        pl[rr] = *(const ushort8*)(eln + off);
      }
    }
    __syncthreads();                    // stores visible

#pragma unroll
    for (int ct = 0; ct < 8; ++ct) {
      const int erow = ct * 16 + col;
      const short8 bh0 = *(const short8*)&eh[erow][quad * 8];
      const short8 bh1 = *(const short8*)&eh[erow][32 + quad * 8];
      const short8 bl0 = *(const short8*)&el[erow][quad * 8];
      const short8 bl1 = *(const short8*)&el[erow][32 + quad * 8];
      f32x4 a0 = {0.f, 0.f, 0.f, 0.f}, a1 = {0.f, 0.f, 0.f, 0.f};
      a0 = __builtin_amdgcn_mfma_f32_16x16x32_bf16(ah[0][0], bh0, a0, 0, 0, 0);
      a1 = __builtin_amdgcn_mfma_f32_16x16x32_bf16(ah[1][0], bh0, a1, 0, 0, 0);
      a0 = __builtin_amdgcn_mfma_f32_16x16x32_bf16(ah[0][1], bh1, a0, 0, 0, 0);
      a1 = __builtin_amdgcn_mfma_f32_16x16x32_bf16(ah[1][1], bh1, a1, 0, 0, 0);
      a0 = __builtin_amdgcn_mfma_f32_16x16x32_bf16(al[0][0], bh0, a0, 0, 0, 0);
      a1 = __builtin_amdgcn_mfma_f32_16x16x32_bf16(al[1][0], bh0, a1, 0, 0, 0);
      a0 = __builtin_amdgcn_mfma_f32_16x16x32_bf16(al[0][1], bh1, a0, 0, 0, 0);
      a1 = __builtin_amdgcn_mfma_f32_16x16x32_bf16(al[1][1], bh1, a1, 0, 0, 0);
      a0 = __builtin_amdgcn_mfma_f32_16x16x32_bf16(ah[0][0], bl0, a0, 0, 0, 0);
      a1 = __builtin_amdgcn_mfma_f32_16x16x32_bf16(ah[1][0], bl0, a1, 0, 0, 0);
      a0 = __builtin_amdgcn_mfma_f32_16x16x32_bf16(ah[0][1], bl1, a0, 0, 0, 0);
      a1 = __builtin_amdgcn_mfma_f32_16x16x32_bf16(ah[1][1], bl1, a1, 0, 0, 0);
      const int m = c * 128 + ct * 16 + col;
      const float sev = se_s[m];
#pragma unroll
      for (int r = 0; r < 4; ++r) {
        const float t0 = fmaf(-2.f, a0[r], sev);
        const bool w0 = t0 < b1[0][r], w0b = t0 < b2[0][r];
        b2[0][r] = w0 ? b1[0][r] : (w0b ? t0 : b2[0][r]);
        b1[0][r] = w0 ? t0 : b1[0][r];
        bi[0][r] = w0 ? m : bi[0][r];
        const float t1 = fmaf(-2.f, a1[r], sev);
        const bool w1 = t1 < b1[1][r], w1b = t1 < b2[1][r];
        b2[1][r] = w1 ? b1[1][r] : (w1b ? t1 : b2[1][r]);
        b1[1][r] = w1 ? t1 : b1[1][r];
        bi[1][r] = w1 ? m : bi[1][r];
      }
    }
  }

  // ---- cross-lane argmin reduce over the 16 cols (first-occurrence ties) ----
#pragma unroll
  for (int off = 1; off <= 8; off <<= 1) {
#pragma unroll
    for (int t = 0; t < 2; ++t)
#pragma unroll
      for (int r = 0; r < 4; ++r) {
        const float o1 = __shfl_xor(b1[t][r], off, 64);
        const float o2 = __shfl_xor(b2[t][r], off, 64);
        const int oi = __shfl_xor(bi[t][r], off, 64);
        const float nb2 = fminf(fmaxf(b1[t][r], o1), fminf(b2[t][r], o2));
        if (o1 < b1[t][r] || (o1 == b1[t][r] && oi < bi[t][r])) {
          b1[t][r] = o1; bi[t][r] = oi;
        }
        b2[t][r] = nb2;
      }
  }
  if (col == 0) {
#pragma unroll
    for (int t = 0; t < 2; ++t)
#pragma unroll
      for (int r = 0; r < 4; ++r) {
        const int kq = q0 + wv * 32 + t * 16 + quad * 4 + r;
        const int bq = kq >> 4, lq = kq & 15;
        const int m = bi[t][r];
        out_idx[(size_t)n * BLQ + kq] = m;
        out[IDX_OFF + (size_t)bq * 64 + n * 16 + lq] = (float)m;
        atomicAdd(&counts[n * M_CB + m], 1u);
        if (b2[t][r] - b1[t][r] < MARGIN_F) {
          const unsigned slot = atomicAdd(nflag, 1u);
          flagged[slot] = (unsigned)(n * BLQ + kq);
        }
      }
  }
}

// -------- kernel 2b (pass B): bit-exact numpy fp32 emulation for flagged ----
__global__ __launch_bounds__(64) void exact_kernel(
    const float* __restrict__ x, const float* __restrict__ emb,
    const float* __restrict__ se, const unsigned* __restrict__ nflag,
    const unsigned* __restrict__ flagged, int* __restrict__ out_idx,
    unsigned* __restrict__ counts, float* __restrict__ out) {
  __shared__ float xs[64];
  const unsigned cnt = *nflag;
  const int lane = threadIdx.x;
  for (unsigned q = blockIdx.x; q < cnt; q += gridDim.x) {
    const unsigned code = flagged[q];
    const int n = code >> 16;          // BLQ == 65536
    const int k = (int)(code & 65535u);
    const int b = k >> 4, l = k & 15;
    __syncthreads();
    xs[lane] = x[(size_t)b * 4096 + (size_t)n * 1024 + lane * 16 + l];
    __syncthreads();
    const float sx = np_sumsq64(xs);
    const float* en  = emb + (size_t)n * (M_CB * D_CB);
    const float* sen = se + (size_t)n * M_CB;
    float bt = 3.4e38f;
    int bm = 0;
    for (int mm = 0; mm < 16; ++mm) {
      const int m = lane * 16 + mm;
      const float* er = en + m * 64;
      float l0 = 0.f, l1 = 0.f, l2 = 0.f, l3 = 0.f;
#pragma unroll
      for (int d = 0; d < 64; d += 4) {
        l0 = __fadd_rn(l0, __fmul_rn(xs[d],     er[d]));
        l1 = __fadd_rn(l1, __fmul_rn(xs[d + 1], er[d + 1]));
        l2 = __fadd_rn(l2, __fmul_rn(xs[d + 2], er[d + 2]));
        l3 = __fadd_rn(l3, __fmul_rn(xs[d + 3], er[d + 3]));
      }
      const float dot = __fadd_rn(__fadd_rn(l3, l2), __fadd_rn(l1, l0));
      const float t = __fsub_rn(__fadd_rn(sx, sen[m]), __fmul_rn(2.0f, dot));
      if (t < bt) { bt = t; bm = m; }
    }
    for (int off = 32; off; off >>= 1) {
      const float ot = __shfl_xor(bt, off, 64);
      const int   om = __shfl_xor(bm, off, 64);
      if (ot < bt || (ot == bt && om < bm)) { bt = ot; bm = om; }
    }
    if (lane == 0) {
      const int old = out_idx[(size_t)n * BLQ + k];
      if (old != bm) {
        out_idx[(size_t)n * BLQ + k] = bm;
        out[IDX_OFF + (size_t)b * 64 + (size_t)n * 16 + l] = (float)bm;
        atomicSub(&counts[n * M_CB + old], 1u);
        atomicAdd(&counts[n * M_CB + bm], 1u);
      }
    }
  }
}

// -------- kernel 3: fused epilogue: z_q, encodings_zq, loss partial, dw ----
__global__ __launch_bounds__(256) void epilogue_kernel(
    const float* __restrict__ x, const float* __restrict__ emb,
    const int* __restrict__ idxs, float* __restrict__ out,
    float* __restrict__ dw, double* __restrict__ loss_acc) {
  const int j = blockIdx.x * 256 + threadIdx.x;
  const size_t i = (size_t)j * 4;                       // 4 consecutive l's
  const int l0 = (int)(i & 15), d = (int)((i >> 4) & 63);
  const int n = (int)((i >> 10) & 3), b = (int)(i >> 12);
  const int kbase = b * 16 + l0;
  const int4 idx4 = *(const int4*)(idxs + (size_t)n * BLQ + kbase);
  const float4 xv = *(const float4*)(x + i);
  const float e0 = emb[((size_t)(n * M_CB + idx4.x) << 6) + d];
  const float e1 = emb[((size_t)(n * M_CB + idx4.y) << 6) + d];
  const float e2 = emb[((size_t)(n * M_CB + idx4.z) << 6) + d];
  const float e3 = emb[((size_t)(n * M_CB + idx4.w) << 6) + d];
  *(float4*)(out + i) = make_float4(e0, e1, e2, e3);
  float2* zq2 = (float2*)(out + ZQ2_OFF + i);           // ZQ2_OFF%4==2: 8B-aligned
  zq2[0] = make_float2(e0, e1);
  zq2[1] = make_float2(e2, e3);
  atomicAdd(&dw[((size_t)(n * M_CB + idx4.x) << 6) + d], xv.x);
  atomicAdd(&dw[((size_t)(n * M_CB + idx4.y) << 6) + d], xv.y);
  atomicAdd(&dw[((size_t)(n * M_CB + idx4.z) << 6) + d], xv.z);
  atomicAdd(&dw[((size_t)(n * M_CB + idx4.w) << 6) + d], xv.w);
  const float d0 = xv.x - e0, d1 = xv.y - e1, d2 = xv.z - e2, d3 = xv.w - e3;
  float v = d0 * d0 + d1 * d1 + d2 * d2 + d3 * d3;
#pragma unroll
  for (int off = 32; off; off >>= 1) v += __shfl_down(v, off, 64);
  __shared__ float part[4];
  if ((threadIdx.x & 63) == 0) part[threadIdx.x >> 6] = v;
  __syncthreads();
  if (threadIdx.x == 0)
    atomicAdd(loss_acc, (double)(part[0] + part[1] + part[2] + part[3]));
}

// -------- kernel 4: smoothed EMA counts + per-codebook entropy --------
__global__ __launch_bounds__(1024) void ema_count_kernel(
    const unsigned* __restrict__ counts, const float* __restrict__ ema_count_in,
    float* __restrict__ out, double* __restrict__ entropy) {
  __shared__ float sdata[1024];
  const int n = blockIdx.x, m = threadIdx.x;
  const unsigned c = counts[n * M_CB + m];
  const float c1 = DECAY_F * ema_count_in[n * M_CB + m] + OMD_F * (float)c;
  sdata[m] = c1;
  __syncthreads();
  for (int s = 512; s > 0; s >>= 1) {
    if (m < s) sdata[m] += sdata[m + s];
    __syncthreads();
  }
  const float nsum = sdata[0];
  __syncthreads();
  out[CNT_OFF + (size_t)n * M_CB + m] = (c1 + EPS_F) / (nsum + MEPS_F) * nsum;
  const float p = (float)c * (1.0f / 65536.0f);
  sdata[m] = p * logf(p + 1e-10f);   // p==0 -> 0 exactly
  __syncthreads();
  for (int s = 512; s > 0; s >>= 1) {
    if (m < s) sdata[m] += sdata[m + s];
    __syncthreads();
  }
  if (m == 0) entropy[n] = -(double)sdata[0];
}

// -------- kernel 5: new_ema_weight + new_embedding --------
__global__ __launch_bounds__(256) void ema_weight_kernel(
    const float* __restrict__ ema_w, const float* __restrict__ dw,
    float* __restrict__ out) {
  const int j = blockIdx.x * 256 + threadIdx.x;  // < N*M*D = 262144
  const float w = DECAY_F * ema_w[j] + OMD_F * dw[j];
  out[EMW_OFF + j] = w;
  out[EMB_OFF + j] = w / out[CNT_OFF + (j >> 6)];
}

// -------- kernel 6: scalars --------
__global__ void scalars_kernel(const double* __restrict__ loss_acc,
                               const double* __restrict__ entropy,
                               float* __restrict__ out) {
  if (threadIdx.x == 0 && blockIdx.x == 0) {
    out[LOSS_OFF] = (float)((double)COMMIT_F * loss_acc[0] * (1.0 / 16777216.0));
    out[PERP_OFF] = (float)(exp(entropy[0]) + exp(entropy[1]) +
                            exp(entropy[2]) + exp(entropy[3]));
  }
}

extern "C" void kernel_launch(void* const* d_in, const int* in_sizes, int n_in,
                              void* d_out, int out_size, void* d_ws, size_t ws_size,
                              hipStream_t stream) {
  const float* x        = (const float*)d_in[0];
  const float* emb      = (const float*)d_in[1];
  const float* ema_cnt  = (const float*)d_in[2];
  const float* ema_wgt  = (const float*)d_in[3];
  float* out = (float*)d_out;
  char* ws = (char*)d_ws;
  unsigned* counts  = (unsigned*)(ws + WS_COUNTS);
  float*    dw      = (float*)(ws + WS_DW);
  unsigned* nflag   = (unsigned*)(ws + WS_NFLAG);
  double*   lacc    = (double*)(ws + WS_LOSS);
  double*   ent     = (double*)(ws + WS_ENT);
  float*    se      = (float*)(ws + WS_SE);
  int*      idxs    = (int*)(ws + WS_IDX);
  unsigned* flagged = (unsigned*)(ws + WS_FLAGGED);
  unsigned short* ehg = (unsigned short*)(ws + WS_EH);
  unsigned short* elg = (unsigned short*)(ws + WS_EL);

  // zero counts+dw+nflag+loss in one shot (ws is poisoned each call)
  hipMemsetAsync(ws, 0, WS_ENT, stream);

  se_kernel<<<16, 256, 0, stream>>>(emb, se);
  ebf_kernel<<<1024, 256, 0, stream>>>(emb, ehg, elg);
  mfma_argmin_kernel<<<dim3(512, 4), 256, 0, stream>>>(
      x, ehg, elg, se, idxs, counts, out, nflag, flagged);
  exact_kernel<<<256, 64, 0, stream>>>(x, emb, se, nflag, flagged, idxs,
                                       counts, out);
  epilogue_kernel<<<16384, 256, 0, stream>>>(x, emb, idxs, out, dw, lacc);
  ema_count_kernel<<<N_CB, 1024, 0, stream>>>(counts, ema_cnt, out, ent);
  ema_weight_kernel<<<1024, 256, 0, stream>>>(ema_wgt, dw, out);
  scalars_kernel<<<1, 64, 0, stream>>>(lacc, ent, out);
}